// Round 3
// baseline (246.968 us; speedup 1.0000x reference)
//
#include <hip/hip_runtime.h>
#include <hip/hip_bf16.h>

#define T_TOK 4096
#define D_IN  2048
#define HS    128

typedef unsigned short u16;
typedef __attribute__((ext_vector_type(8))) __bf16 bf16x8;
typedef __attribute__((ext_vector_type(4))) float f32x4;
typedef __attribute__((ext_vector_type(4))) unsigned short us4;
typedef __attribute__((ext_vector_type(8))) unsigned short us8;

#define GLOBAL_AS __attribute__((address_space(1)))
#define LDS_AS    __attribute__((address_space(3)))

__device__ __forceinline__ void async_ld16(const void* g, void* l) {
  __builtin_amdgcn_global_load_lds((GLOBAL_AS void*)(void*)g, (LDS_AS void*)l, 16, 0, 0);
}

__device__ __forceinline__ u16 f2bf(float v) {
  return __builtin_bit_cast(u16, __float2bfloat16(v));
}

// ---------------------------------------------------------------------------
// Input normalizer: detects whether `in` holds fp32 or bf16 data, writes a
// clean bf16 copy to `out`. Detection: even-indexed u16s of fp32 data are raw
// low-mantissa bits -> ~25% have "exponent" field >= 0xBF; genuine bf16
// N(0,sigma) data has none. Optionally publishes the flag to *flag so the
// epilogue can store the matching output dtype.
// ---------------------------------------------------------------------------
__global__ __launch_bounds__(256) void conv_kernel(
    const u16* __restrict__ in, u16* __restrict__ out, int n,
    int* __restrict__ flag, int write_flag)
{
  __shared__ int sflag;
  const int tid = threadIdx.x;
  if (tid < 64) {
    int cnt = 0;
#pragma unroll
    for (int j = 0; j < 8; j++) {
      u16 v = in[(tid * 8 + j) * 2];
      cnt += (((v >> 7) & 0xFF) >= 0xBF) ? 1 : 0;
    }
#pragma unroll
    for (int off = 1; off < 64; off <<= 1) cnt += __shfl_xor(cnt, off);
    if (tid == 0) sflag = (cnt > 8) ? 1 : 0;
  }
  __syncthreads();
  const bool isf32 = (sflag != 0);
  if (tid == 0 && write_flag) *flag = isf32 ? 1 : 0;
  const size_t base = ((size_t)blockIdx.x * 256 + tid) * 8;
  if (base >= (size_t)n) return;
  if (isf32) {
    const float* f = (const float*)in;
    us4 a, b;
#pragma unroll
    for (int j = 0; j < 4; j++) a[j] = f2bf(f[base + j]);
#pragma unroll
    for (int j = 0; j < 4; j++) b[j] = f2bf(f[base + 4 + j]);
    *(us4*)(out + base) = a;
    *(us4*)(out + base + 4) = b;
  } else {
    *(us8*)(out + base) = *(const us8*)(in + base);
  }
}

// ---------------------------------------------------------------------------
// QKV projection: Q = x Wq^T, K = x Wk^T, V^T (transposed) = (x Wv^T)^T
// grid (64 m-tiles, 3 mats), block 256 (4 waves). BM=64, BN=128, BK=64.
// LDS tiles stored as XOR-swizzled 16B chunks: chunk (row r, c) at slot
// r*8 + (c ^ (r&7))  -> ds_read_b128 frag reads are 2-way-conflict (free).
// ---------------------------------------------------------------------------
__global__ __launch_bounds__(256, 2) void qkv_kernel(
    const u16* __restrict__ x, const u16* __restrict__ Wq,
    const u16* __restrict__ Wk, const u16* __restrict__ Wv,
    u16* __restrict__ Q, u16* __restrict__ K, u16* __restrict__ Vt)
{
  __shared__ __align__(16) u16 As[64 * 64];    // 8 KB  (x tile)
  __shared__ __align__(16) u16 Bs[128 * 64];   // 16 KB (W tile)

  const int mat = blockIdx.y;
  const u16* W = (mat == 0) ? Wq : ((mat == 1) ? Wk : Wv);
  const int mtile = blockIdx.x;
  const int tid = threadIdx.x;
  const int wv = tid >> 6, lane = tid & 63, l15 = lane & 15, quad = lane >> 4;
  const int row0 = mtile * 64;

  f32x4 acc[8];
#pragma unroll
  for (int i = 0; i < 8; i++) acc[i] = (f32x4)0.0f;

  for (int k0 = 0; k0 < D_IN; k0 += 64) {
    __syncthreads();
    // stage A: 64x64 bf16 = 512 chunks, 2 loads/wave
#pragma unroll
    for (int j = 0; j < 2; j++) {
      int s = (wv * 2 + j) * 64 + lane;
      int r = s >> 3, cs = s & 7, c = cs ^ (r & 7);
      async_ld16(x + (size_t)(row0 + r) * D_IN + k0 + c * 8,
                 (char*)As + (size_t)(wv * 2 + j) * 1024);
    }
    // stage B: 128x64 bf16 = 1024 chunks, 4 loads/wave
#pragma unroll
    for (int j = 0; j < 4; j++) {
      int s = (wv * 4 + j) * 64 + lane;
      int n = s >> 3, cs = s & 7, c = cs ^ (n & 7);
      async_ld16(W + (size_t)n * D_IN + k0 + c * 8,
                 (char*)Bs + (size_t)(wv * 4 + j) * 1024);
    }
    __syncthreads();

#pragma unroll
    for (int kc = 0; kc < 2; kc++) {
      const int rA = 16 * wv + l15;
      const int cl = kc * 4 + quad;
      bf16x8 a = *(const bf16x8*)((const char*)As + (rA * 8 + (cl ^ (rA & 7))) * 16);
#pragma unroll
      for (int nt = 0; nt < 8; nt++) {
        int n = 16 * nt + l15;
        bf16x8 b = *(const bf16x8*)((const char*)Bs + (n * 8 + (cl ^ (n & 7))) * 16);
        acc[nt] = __builtin_amdgcn_mfma_f32_16x16x32_bf16(a, b, acc[nt], 0, 0, 0);
      }
    }
  }

  // epilogue. D-frag: row = quad*4 + r (within wave's 16-row band), col = 16*nt + l15
  if (mat < 2) {
    u16* out = (mat == 0) ? Q : K;
#pragma unroll
    for (int nt = 0; nt < 8; nt++)
#pragma unroll
      for (int r = 0; r < 4; r++) {
        int m = row0 + 16 * wv + quad * 4 + r;
        int n = 16 * nt + l15;
        out[(size_t)m * HS + n] = f2bf(acc[nt][r]);
      }
  } else {
    // write V transposed: Vt[n][m], 4 consecutive m per lane -> 8B store
#pragma unroll
    for (int nt = 0; nt < 8; nt++) {
      int n = 16 * nt + l15;
      int mb = row0 + 16 * wv + quad * 4;
      us4 pk;
#pragma unroll
      for (int r = 0; r < 4; r++) pk[r] = f2bf(acc[nt][r]);
      *(us4*)(Vt + (size_t)n * T_TOK + mb) = pk;
    }
  }
}

// ---------------------------------------------------------------------------
// Flash attention, causal. One block per 64 Q rows, 4 waves x 16 rows.
// KV step = 64 rows. Q frags live in registers across all steps.
// Output dtype follows *dflag (1 = fp32, 0 = bf16).
// ---------------------------------------------------------------------------
__global__ __launch_bounds__(256, 2) void attn_kernel(
    const u16* __restrict__ Q, const u16* __restrict__ Kg,
    const u16* __restrict__ Vt, void* __restrict__ out_v,
    const int* __restrict__ dflag)
{
  __shared__ __align__(16) u16 Ks[64 * 128];    // 16 KB
  __shared__ __align__(16) u16 Vs[128 * 64];    // 16 KB (V^T tile)
  __shared__ __align__(16) u16 Ps[4 * 16 * 64]; // 8 KB (per-wave P)

  const int qtile = (int)gridDim.x - 1 - (int)blockIdx.x; // heavy blocks first
  const int q0 = qtile * 64;
  const int tid = threadIdx.x;
  const int wv = tid >> 6, lane = tid & 63, l15 = lane & 15, quad = lane >> 4;
  const bool of32 = (*dflag != 0);

  // Q A-frags: A[m=l15][k=quad*8+j], 4 k-chunks of 32
  bf16x8 qf[4];
#pragma unroll
  for (int kc = 0; kc < 4; kc++)
    qf[kc] = *(const bf16x8*)(Q + (size_t)(q0 + 16 * wv + l15) * HS + kc * 32 + quad * 8);

  f32x4 o[8];
#pragma unroll
  for (int i = 0; i < 8; i++) o[i] = (f32x4)0.0f;
  float mrun[4], lrun[4];
#pragma unroll
  for (int r = 0; r < 4; r++) { mrun[r] = -1e30f; lrun[r] = 0.0f; }

  const float sc = 0.12752761571239668f; // log2(e)/sqrt(128)
  const int nsteps = qtile + 1;

  for (int st = 0; st < nsteps; st++) {
    const int k0 = st * 64;
    __syncthreads();
    // stage K tile 64x128: 1024 chunks (16 chunks/row, swizzled)
#pragma unroll
    for (int j = 0; j < 4; j++) {
      int s = (wv * 4 + j) * 64 + lane;
      int n = s >> 4, cs = s & 15, c = cs ^ (n & 7);
      async_ld16(Kg + (size_t)(k0 + n) * HS + c * 8,
                 (char*)Ks + (size_t)(wv * 4 + j) * 1024);
    }
    // stage Vt tile 128x64: 1024 chunks (8 chunks/row, swizzled)
#pragma unroll
    for (int j = 0; j < 4; j++) {
      int s = (wv * 4 + j) * 64 + lane;
      int vr = s >> 3, cs = s & 7, c = cs ^ (vr & 7);
      async_ld16(Vt + (size_t)vr * T_TOK + k0 + c * 8,
                 (char*)Vs + (size_t)(wv * 4 + j) * 1024);
    }
    __syncthreads();

    // S = Q K^T (16 rows x 64 cols per wave)
    f32x4 sacc[4];
#pragma unroll
    for (int nt = 0; nt < 4; nt++) sacc[nt] = (f32x4)0.0f;
#pragma unroll
    for (int kc = 0; kc < 4; kc++) {
      const int cl = kc * 4 + quad;
#pragma unroll
      for (int nt = 0; nt < 4; nt++) {
        int n = 16 * nt + l15;
        bf16x8 b = *(const bf16x8*)((const char*)Ks + (n * 16 + (cl ^ (n & 7))) * 16);
        sacc[nt] = __builtin_amdgcn_mfma_f32_16x16x32_bf16(qf[kc], b, sacc[nt], 0, 0, 0);
      }
    }

    // scale into log2 domain + causal mask (only the diagonal tile)
    float s2[4][4];
    const bool diag = (st == qtile);
#pragma unroll
    for (int nt = 0; nt < 4; nt++)
#pragma unroll
      for (int r = 0; r < 4; r++) {
        float v = sacc[nt][r] * sc;
        if (diag) {
          int qr = q0 + 16 * wv + quad * 4 + r;
          int kr = k0 + 16 * nt + l15;
          if (kr > qr) v = -1e30f;
        }
        s2[nt][r] = v;
      }

    // online softmax stats; each row lives in 16 lanes of one quad
    float mnew[4], alpha[4];
#pragma unroll
    for (int r = 0; r < 4; r++) {
      float t = fmaxf(fmaxf(s2[0][r], s2[1][r]), fmaxf(s2[2][r], s2[3][r]));
#pragma unroll
      for (int off = 1; off < 16; off <<= 1) t = fmaxf(t, __shfl_xor(t, off));
      mnew[r] = fmaxf(mrun[r], t);
      alpha[r] = exp2f(mrun[r] - mnew[r]);
      mrun[r] = mnew[r];
    }
    float p[4][4];
#pragma unroll
    for (int r = 0; r < 4; r++) {
      float s = 0.0f;
#pragma unroll
      for (int nt = 0; nt < 4; nt++) { p[nt][r] = exp2f(s2[nt][r] - mnew[r]); s += p[nt][r]; }
#pragma unroll
      for (int off = 1; off < 16; off <<= 1) s += __shfl_xor(s, off);
      lrun[r] = lrun[r] * alpha[r] + s;
    }
    // rescale O accumulator
#pragma unroll
    for (int c = 0; c < 8; c++)
#pragma unroll
      for (int r = 0; r < 4; r++) o[c][r] *= alpha[r];

    // P: C-layout -> LDS (bf16, swizzled) -> A-layout
    u16* Pw = Ps + wv * 1024;
#pragma unroll
    for (int nt = 0; nt < 4; nt++)
#pragma unroll
      for (int r = 0; r < 4; r++) {
        int row = quad * 4 + r;
        int col = nt * 16 + l15;
        int ch = col >> 3, wi = col & 7;
        Pw[(row * 8 + (ch ^ (row & 7))) * 8 + wi] = f2bf(p[nt][r]);
      }
    __syncthreads();

    // O += P V  (K-dim 64 -> 2 chained MFMAs, 8 col-tiles)
#pragma unroll
    for (int kc = 0; kc < 2; kc++) {
      const int cl = kc * 4 + quad;
      bf16x8 a = *(const bf16x8*)((const char*)Pw + (l15 * 8 + (cl ^ (l15 & 7))) * 16);
#pragma unroll
      for (int c = 0; c < 8; c++) {
        int vr = 16 * c + l15;
        bf16x8 b = *(const bf16x8*)((const char*)Vs + (vr * 8 + (cl ^ (vr & 7))) * 16);
        o[c] = __builtin_amdgcn_mfma_f32_16x16x32_bf16(a, b, o[c], 0, 0, 0);
      }
    }
  }

  // normalize + store (dtype per detected input dtype)
  if (of32) {
    float* out = (float*)out_v;
#pragma unroll
    for (int c = 0; c < 8; c++)
#pragma unroll
      for (int r = 0; r < 4; r++) {
        int m = q0 + 16 * wv + quad * 4 + r;
        int n = 16 * c + l15;
        out[(size_t)m * HS + n] = o[c][r] / lrun[r];
      }
  } else {
    u16* out = (u16*)out_v;
#pragma unroll
    for (int c = 0; c < 8; c++)
#pragma unroll
      for (int r = 0; r < 4; r++) {
        int m = q0 + 16 * wv + quad * 4 + r;
        int n = 16 * c + l15;
        out[(size_t)m * HS + n] = f2bf(o[c][r] / lrun[r]);
      }
  }
}

extern "C" void kernel_launch(void* const* d_in, const int* in_sizes, int n_in,
                              void* d_out, int out_size, void* d_ws, size_t ws_size,
                              hipStream_t stream) {
  const u16* x  = (const u16*)d_in[0];
  const u16* Wq = (const u16*)d_in[1];
  const u16* Wk = (const u16*)d_in[2];
  const u16* Wv = (const u16*)d_in[3];

  // ws layout (u16 units)
  u16* xb  = (u16*)d_ws;                         // 4096*2048
  u16* Wqb = xb  + (size_t)T_TOK * D_IN;         // 128*2048
  u16* Wkb = Wqb + (size_t)HS * D_IN;
  u16* Wvb = Wkb + (size_t)HS * D_IN;
  u16* Q   = Wvb + (size_t)HS * D_IN;            // 4096*128
  u16* K   = Q   + (size_t)T_TOK * HS;
  u16* Vt  = K   + (size_t)T_TOK * HS;
  int* flag = (int*)(Vt + (size_t)T_TOK * HS);

  const int nx = T_TOK * D_IN;   // 8388608
  const int nw = HS * D_IN;      // 262144
  conv_kernel<<<nx / 2048, 256, 0, stream>>>(x,  xb,  nx, flag, 1);
  conv_kernel<<<nw / 2048, 256, 0, stream>>>(Wq, Wqb, nw, flag, 0);
  conv_kernel<<<nw / 2048, 256, 0, stream>>>(Wk, Wkb, nw, flag, 0);
  conv_kernel<<<nw / 2048, 256, 0, stream>>>(Wv, Wvb, nw, flag, 0);

  qkv_kernel<<<dim3(64, 3), 256, 0, stream>>>(xb, Wqb, Wkb, Wvb, Q, K, Vt);
  attn_kernel<<<64, 256, 0, stream>>>(Q, K, Vt, d_out, flag);
}

// Round 5
// 151.667 us; speedup vs baseline: 1.6284x; 1.6284x over previous
//
#include <hip/hip_runtime.h>
#include <hip/hip_bf16.h>

#define T_TOK 4096
#define D_IN  2048
#define HS    128
#define CKV   4      // KV tiles per attention chunk
#define NCH   16     // ceil(64 / CKV)

typedef unsigned short u16;
typedef __attribute__((ext_vector_type(8))) __bf16 bf16x8;
typedef __attribute__((ext_vector_type(4))) float f32x4;
typedef __attribute__((ext_vector_type(4))) unsigned short us4;
typedef __attribute__((ext_vector_type(8))) unsigned short us8;

#define GLOBAL_AS __attribute__((address_space(1)))
#define LDS_AS    __attribute__((address_space(3)))

__device__ __forceinline__ void async_ld16(const void* g, void* l) {
  __builtin_amdgcn_global_load_lds((GLOBAL_AS void*)(void*)g, (LDS_AS void*)l, 16, 0, 0);
}

__device__ __forceinline__ u16 f2bf(float v) {
  return __builtin_bit_cast(u16, __float2bfloat16(v));
}

// ---------------------------------------------------------------------------
// Input normalizer (fp32-vs-bf16 autodetect; writes bf16). Detection: even
// u16s of fp32 data are raw low-mantissa bits -> ~25% have "exponent" >= 0xBF;
// genuine bf16 N(0,s) has none. x-instance publishes flag for output dtype.
// ---------------------------------------------------------------------------
__device__ __forceinline__ void conv_body(const u16* in, u16* out, int n,
                                          int* flag, int write_flag,
                                          int blk, int tid) {
  __shared__ int sflag;
  if (tid < 64) {
    int cnt = 0;
#pragma unroll
    for (int j = 0; j < 8; j++) {
      u16 v = in[(tid * 8 + j) * 2];
      cnt += (((v >> 7) & 0xFF) >= 0xBF) ? 1 : 0;
    }
#pragma unroll
    for (int off = 1; off < 64; off <<= 1) cnt += __shfl_xor(cnt, off);
    if (tid == 0) sflag = (cnt > 8) ? 1 : 0;
  }
  __syncthreads();
  const bool isf32 = (sflag != 0);
  if (tid == 0 && write_flag && blk == 0) *flag = isf32 ? 1 : 0;
  const size_t base = ((size_t)blk * 256 + tid) * 8;
  if (base >= (size_t)n) return;
  if (isf32) {
    const float* f = (const float*)in;
    us4 a, b;
#pragma unroll
    for (int j = 0; j < 4; j++) a[j] = f2bf(f[base + j]);
#pragma unroll
    for (int j = 0; j < 4; j++) b[j] = f2bf(f[base + 4 + j]);
    *(us4*)(out + base) = a;
    *(us4*)(out + base + 4) = b;
  } else {
    *(us8*)(out + base) = *(const us8*)(in + base);
  }
}

__global__ __launch_bounds__(256) void conv_kernel(
    const u16* __restrict__ in, u16* __restrict__ out, int n,
    int* __restrict__ flag) {
  conv_body(in, out, n, flag, 1, blockIdx.x, threadIdx.x);
}

// all three weight matrices in one launch: 128 blocks per matrix
__global__ __launch_bounds__(256) void conv3_kernel(
    const u16* __restrict__ w0, const u16* __restrict__ w1,
    const u16* __restrict__ w2, u16* __restrict__ o0,
    u16* __restrict__ o1, u16* __restrict__ o2) {
  const int mat = blockIdx.x >> 7;
  const int blk = blockIdx.x & 127;
  const u16* in = (mat == 0) ? w0 : ((mat == 1) ? w1 : w2);
  u16* out = (mat == 0) ? o0 : ((mat == 1) ? o1 : o2);
  conv_body(in, out, HS * D_IN, nullptr, 0, blk, threadIdx.x);
}

// ---------------------------------------------------------------------------
// QKV projection, double-buffered LDS. grid (64 m-tiles, 3 mats), 4 waves.
// Swizzled 16B chunks: chunk (row r, c) at slot r*W + (c ^ (r&7)).
// ---------------------------------------------------------------------------
__global__ __launch_bounds__(256, 2) void qkv_kernel(
    const u16* __restrict__ x, const u16* __restrict__ Wq,
    const u16* __restrict__ Wk, const u16* __restrict__ Wv,
    u16* __restrict__ Q, u16* __restrict__ K, u16* __restrict__ Vt)
{
  __shared__ __align__(16) u16 As[2][64 * 64];    // 2 x 8 KB
  __shared__ __align__(16) u16 Bs[2][128 * 64];   // 2 x 16 KB

  const int mat = blockIdx.y;
  const u16* W = (mat == 0) ? Wq : ((mat == 1) ? Wk : Wv);
  const int mtile = blockIdx.x;
  const int tid = threadIdx.x;
  const int wv = tid >> 6, lane = tid & 63, l15 = lane & 15, quad = lane >> 4;
  const int row0 = mtile * 64;

  f32x4 acc[8];
#pragma unroll
  for (int i = 0; i < 8; i++) acc[i] = (f32x4)0.0f;

  auto stage = [&](int k0, int buf) {
#pragma unroll
    for (int j = 0; j < 2; j++) {
      int s = (wv * 2 + j) * 64 + lane;
      int r = s >> 3, cs = s & 7, c = cs ^ (r & 7);
      async_ld16(x + (size_t)(row0 + r) * D_IN + k0 + c * 8,
                 (char*)As[buf] + (size_t)(wv * 2 + j) * 1024);
    }
#pragma unroll
    for (int j = 0; j < 4; j++) {
      int s = (wv * 4 + j) * 64 + lane;
      int n = s >> 3, cs = s & 7, c = cs ^ (n & 7);
      async_ld16(W + (size_t)n * D_IN + k0 + c * 8,
                 (char*)Bs[buf] + (size_t)(wv * 4 + j) * 1024);
    }
  };

  stage(0, 0);
  for (int kt = 0; kt < 32; kt++) {
    const int cur = kt & 1;
    __syncthreads();                       // drains loads for buf cur
    if (kt < 31) stage((kt + 1) * 64, 1 - cur);  // prefetch overlaps compute
#pragma unroll
    for (int kc = 0; kc < 2; kc++) {
      const int rA = 16 * wv + l15;
      const int cl = kc * 4 + quad;
      bf16x8 a = *(const bf16x8*)((const char*)As[cur] + (rA * 8 + (cl ^ (rA & 7))) * 16);
#pragma unroll
      for (int nt = 0; nt < 8; nt++) {
        int n = 16 * nt + l15;
        bf16x8 b = *(const bf16x8*)((const char*)Bs[cur] + (n * 8 + (cl ^ (n & 7))) * 16);
        acc[nt] = __builtin_amdgcn_mfma_f32_16x16x32_bf16(a, b, acc[nt], 0, 0, 0);
      }
    }
  }

  // epilogue. D-frag: row = quad*4 + r, col = 16*nt + l15
  if (mat < 2) {
    u16* out = (mat == 0) ? Q : K;
#pragma unroll
    for (int nt = 0; nt < 8; nt++)
#pragma unroll
      for (int r = 0; r < 4; r++) {
        int m = row0 + 16 * wv + quad * 4 + r;
        int n = 16 * nt + l15;
        out[(size_t)m * HS + n] = f2bf(acc[nt][r]);
      }
  } else {
#pragma unroll
    for (int nt = 0; nt < 8; nt++) {
      int n = 16 * nt + l15;
      int mb = row0 + 16 * wv + quad * 4;
      us4 pk;
#pragma unroll
      for (int r = 0; r < 4; r++) pk[r] = f2bf(acc[nt][r]);
      *(us4*)(Vt + (size_t)n * T_TOK + mb) = pk;
    }
  }
}

// ---------------------------------------------------------------------------
// Split-KV flash attention. grid (64 qtiles, NCH chunks); block (qtile,ch)
// handles KV tiles [4ch, min(4ch+3, qtile)] and emits fp32 partial O + m,l.
// Dense slot index: slot(q,ch) = 64*ch - 2*ch*(ch-1) + (q - 4*ch).
// ---------------------------------------------------------------------------
__global__ __launch_bounds__(256, 2) void attn_split_kernel(
    const u16* __restrict__ Q, const u16* __restrict__ Kg,
    const u16* __restrict__ Vt, float* __restrict__ Opart,
    float* __restrict__ mstat, float* __restrict__ lstat)
{
  __shared__ __align__(16) u16 Ks[2][64 * 128];   // 2 x 16 KB
  __shared__ __align__(16) u16 Vs[2][128 * 64];   // 2 x 16 KB
  __shared__ __align__(16) u16 Ps[4 * 16 * 64];   // 8 KB (per-wave P)

  const int qtile = 63 - (int)blockIdx.x;         // heavy blocks first
  const int ch = blockIdx.y;
  if (4 * ch > qtile) return;
  const int t0 = 4 * ch;
  const int nsteps = min(CKV, qtile + 1 - t0);
  const int q0 = qtile * 64;
  const int slot = 64 * ch - 2 * ch * (ch - 1) + (qtile - 4 * ch);

  const int tid = threadIdx.x;
  const int wv = tid >> 6, lane = tid & 63, l15 = lane & 15, quad = lane >> 4;

  // Q A-frags: A[m=l15][k=quad*8+j]
  bf16x8 qf[4];
#pragma unroll
  for (int kc = 0; kc < 4; kc++)
    qf[kc] = *(const bf16x8*)(Q + (size_t)(q0 + 16 * wv + l15) * HS + kc * 32 + quad * 8);

  f32x4 o[8];
#pragma unroll
  for (int i = 0; i < 8; i++) o[i] = (f32x4)0.0f;
  float mrun[4], lrun[4];
#pragma unroll
  for (int r = 0; r < 4; r++) { mrun[r] = -1e30f; lrun[r] = 0.0f; }

  const float sc = 0.12752761571239668f; // log2(e)/sqrt(128)

  auto stage = [&](int t, int buf) {
#pragma unroll
    for (int j = 0; j < 4; j++) {
      int s = (wv * 4 + j) * 64 + lane;
      int n = s >> 4, cs = s & 15, c = cs ^ (n & 7);
      async_ld16(Kg + (size_t)(t * 64 + n) * HS + c * 8,
                 (char*)Ks[buf] + (size_t)(wv * 4 + j) * 1024);
    }
#pragma unroll
    for (int j = 0; j < 4; j++) {
      int s = (wv * 4 + j) * 64 + lane;
      int vr = s >> 3, cs = s & 7, c = cs ^ (vr & 7);
      async_ld16(Vt + (size_t)vr * T_TOK + t * 64 + c * 8,
                 (char*)Vs[buf] + (size_t)(wv * 4 + j) * 1024);
    }
  };

  stage(t0, 0);
  for (int i = 0; i < nsteps; i++) {
    const int cur = i & 1;
    const int t = t0 + i;
    __syncthreads();                           // drains loads for buf cur
    if (i + 1 < nsteps) stage(t + 1, 1 - cur); // prefetch overlaps compute

    // S = Q K^T
    f32x4 sacc[4];
#pragma unroll
    for (int nt = 0; nt < 4; nt++) sacc[nt] = (f32x4)0.0f;
#pragma unroll
    for (int kc = 0; kc < 4; kc++) {
      const int cl = kc * 4 + quad;
#pragma unroll
      for (int nt = 0; nt < 4; nt++) {
        int n = 16 * nt + l15;
        bf16x8 b = *(const bf16x8*)((const char*)Ks[cur] + (n * 16 + (cl ^ (n & 7))) * 16);
        sacc[nt] = __builtin_amdgcn_mfma_f32_16x16x32_bf16(qf[kc], b, sacc[nt], 0, 0, 0);
      }
    }

    // scale into log2 domain + causal mask (diagonal tile only)
    float s2[4][4];
    const bool diag = (t == qtile);
#pragma unroll
    for (int nt = 0; nt < 4; nt++)
#pragma unroll
      for (int r = 0; r < 4; r++) {
        float v = sacc[nt][r] * sc;
        if (diag) {
          int qr = q0 + 16 * wv + quad * 4 + r;
          int kr = t * 64 + 16 * nt + l15;
          if (kr > qr) v = -1e30f;
        }
        s2[nt][r] = v;
      }

    // online softmax; each row lives in the 16 lanes of one quad
    float mnew[4], alpha[4];
#pragma unroll
    for (int r = 0; r < 4; r++) {
      float tmax = fmaxf(fmaxf(s2[0][r], s2[1][r]), fmaxf(s2[2][r], s2[3][r]));
#pragma unroll
      for (int off = 1; off < 16; off <<= 1) tmax = fmaxf(tmax, __shfl_xor(tmax, off));
      mnew[r] = fmaxf(mrun[r], tmax);
      alpha[r] = exp2f(mrun[r] - mnew[r]);
      mrun[r] = mnew[r];
    }
    float p[4][4];
#pragma unroll
    for (int r = 0; r < 4; r++) {
      float s = 0.0f;
#pragma unroll
      for (int nt = 0; nt < 4; nt++) { p[nt][r] = exp2f(s2[nt][r] - mnew[r]); s += p[nt][r]; }
#pragma unroll
      for (int off = 1; off < 16; off <<= 1) s += __shfl_xor(s, off);
      lrun[r] = lrun[r] * alpha[r] + s;
    }
#pragma unroll
    for (int c = 0; c < 8; c++)
#pragma unroll
      for (int r = 0; r < 4; r++) o[c][r] *= alpha[r];

    // P: C-layout -> per-wave LDS (no barrier needed; DS ops are in-order
    // within a wave and Ps is wave-private)
    u16* Pw = Ps + wv * 1024;
#pragma unroll
    for (int nt = 0; nt < 4; nt++)
#pragma unroll
      for (int r = 0; r < 4; r++) {
        int row = quad * 4 + r;
        int col = nt * 16 + l15;
        int cc = col >> 3, wi = col & 7;
        Pw[(row * 8 + (cc ^ (row & 7))) * 8 + wi] = f2bf(p[nt][r]);
      }

    // O += P V
#pragma unroll
    for (int kc = 0; kc < 2; kc++) {
      const int cl = kc * 4 + quad;
      bf16x8 a = *(const bf16x8*)((const char*)Pw + (l15 * 8 + (cl ^ (l15 & 7))) * 16);
#pragma unroll
      for (int c = 0; c < 8; c++) {
        int vr = 16 * c + l15;
        bf16x8 b = *(const bf16x8*)((const char*)Vs[cur] + (vr * 8 + (cl ^ (vr & 7))) * 16);
        o[c] = __builtin_amdgcn_mfma_f32_16x16x32_bf16(a, b, o[c], 0, 0, 0);
      }
    }
  }

  // store fp32 partial O + stats
  float* po = Opart + (size_t)slot * 64 * 128;
#pragma unroll
  for (int c = 0; c < 8; c++)
#pragma unroll
    for (int r = 0; r < 4; r++) {
      int ml = 16 * wv + quad * 4 + r;
      po[ml * 128 + 16 * c + l15] = o[c][r];
    }
  if (l15 == 0) {
#pragma unroll
    for (int r = 0; r < 4; r++) {
      int ml = 16 * wv + quad * 4 + r;
      mstat[slot * 64 + ml] = mrun[r];
      lstat[slot * 64 + ml] = lrun[r];
    }
  }
}

// ---------------------------------------------------------------------------
// Combine partials. grid (64 qtiles, 4 col-blocks), 256 threads.
// Thread handles one row x 8 cols. Output dtype per detected flag.
// ---------------------------------------------------------------------------
__global__ __launch_bounds__(256) void combine_kernel(
    const float* __restrict__ Opart, const float* __restrict__ mstat,
    const float* __restrict__ lstat, void* __restrict__ out_v,
    const int* __restrict__ dflag)
{
  const int q = blockIdx.x;
  const int cb = blockIdx.y;
  const int tid = threadIdx.x;
  const int row = tid >> 2;
  const int col = cb * 32 + (tid & 3) * 8;
  const int nch = (q + 4) / 4;   // ceil((q+1)/4)
  const bool of32 = (*dflag != 0);

  float M = -1e30f;
  {
    int base = 0;
    for (int c = 0; c < nch; c++) {
      int s = base + q - 4 * c;
      M = fmaxf(M, mstat[s * 64 + row]);
      base += 64 - 4 * c;
    }
  }
  float l = 0.0f;
  float acc[8];
#pragma unroll
  for (int j = 0; j < 8; j++) acc[j] = 0.0f;
  {
    int base = 0;
    for (int c = 0; c < nch; c++) {
      int s = base + q - 4 * c;
      float w = exp2f(mstat[s * 64 + row] - M);
      l += w * lstat[s * 64 + row];
      const float* op = Opart + ((size_t)s * 64 + row) * 128 + col;
      f32x4 a = *(const f32x4*)op;
      f32x4 b = *(const f32x4*)(op + 4);
#pragma unroll
      for (int j = 0; j < 4; j++) { acc[j] += w * a[j]; acc[4 + j] += w * b[j]; }
      base += 64 - 4 * c;
    }
  }
  const float inv = 1.0f / l;
  const size_t goff = (size_t)(q * 64 + row) * HS + col;
  if (of32) {
    float* out = (float*)out_v + goff;
    f32x4 r0, r1;
#pragma unroll
    for (int j = 0; j < 4; j++) { r0[j] = acc[j] * inv; r1[j] = acc[4 + j] * inv; }
    *(f32x4*)out = r0;
    *(f32x4*)(out + 4) = r1;
  } else {
    u16* out = (u16*)out_v + goff;
    us4 r0, r1;
#pragma unroll
    for (int j = 0; j < 4; j++) { r0[j] = f2bf(acc[j] * inv); r1[j] = f2bf(acc[4 + j] * inv); }
    *(us4*)out = r0;
    *(us4*)(out + 4) = r1;
  }
}

extern "C" void kernel_launch(void* const* d_in, const int* in_sizes, int n_in,
                              void* d_out, int out_size, void* d_ws, size_t ws_size,
                              hipStream_t stream) {
  const u16* x  = (const u16*)d_in[0];
  const u16* Wq = (const u16*)d_in[1];
  const u16* Wk = (const u16*)d_in[2];
  const u16* Wv = (const u16*)d_in[3];

  // ws layout (u16 units). xb + W region (18.35 MB) is DEAD after qkv_kernel
  // and is reused for the 544 fp32 attention partials (17.8 MB + stats,
  // ending at 18.10 MB < 18.35 MB where Q begins).
  u16* xb  = (u16*)d_ws;                         // 4096*2048 bf16
  u16* Wqb = xb  + (size_t)T_TOK * D_IN;
  u16* Wkb = Wqb + (size_t)HS * D_IN;
  u16* Wvb = Wkb + (size_t)HS * D_IN;
  u16* Q   = Wvb + (size_t)HS * D_IN;            // live through combine
  u16* K   = Q   + (size_t)T_TOK * HS;
  u16* Vt  = K   + (size_t)T_TOK * HS;
  int* flag = (int*)(Vt + (size_t)T_TOK * HS);

  float* Opart = (float*)d_ws;                   // 544 * 64*128 fp32
  float* mstat = Opart + (size_t)544 * 64 * 128;
  float* lstat = mstat + (size_t)544 * 64;

  const int nx = T_TOK * D_IN;
  conv_kernel<<<nx / 2048, 256, 0, stream>>>(x, xb, nx, flag);
  conv3_kernel<<<384, 256, 0, stream>>>(Wq, Wk, Wv, Wqb, Wkb, Wvb);

  qkv_kernel<<<dim3(64, 3), 256, 0, stream>>>(xb, Wqb, Wkb, Wvb, Q, K, Vt);
  attn_split_kernel<<<dim3(64, NCH), 256, 0, stream>>>(Q, K, Vt, Opart, mstat, lstat);
  combine_kernel<<<dim3(64, 4), 256, 0, stream>>>(Opart, mstat, lstat, d_out, flag);
}

// Round 7
// 147.591 us; speedup vs baseline: 1.6733x; 1.0276x over previous
//
#include <hip/hip_runtime.h>
#include <hip/hip_bf16.h>

#define T_TOK 4096
#define D_IN  2048
#define HS    128
#define CKV   4      // KV tiles per attention chunk
#define NCH   16     // ceil(64 / CKV)

typedef unsigned short u16;
typedef __attribute__((ext_vector_type(8))) __bf16 bf16x8;
typedef __attribute__((ext_vector_type(4))) float f32x4;
typedef __attribute__((ext_vector_type(4))) unsigned short us4;
typedef __attribute__((ext_vector_type(8))) unsigned short us8;

#define GLOBAL_AS __attribute__((address_space(1)))
#define LDS_AS    __attribute__((address_space(3)))

__device__ __forceinline__ void async_ld16(const void* g, void* l) {
  __builtin_amdgcn_global_load_lds((GLOBAL_AS void*)(void*)g, (LDS_AS void*)l, 16, 0, 0);
}

__device__ __forceinline__ u16 f2bf(float v) {
  return __builtin_bit_cast(u16, __float2bfloat16(v));
}

// ---------------------------------------------------------------------------
// fp32-vs-bf16 autodetect on a buffer head: even u16s of fp32 data are raw
// low-mantissa bits -> ~25% have "exponent" field >= 0xBF; genuine bf16
// N(0,s) has none. Returns wave-uniform flag via LDS broadcast.
// ---------------------------------------------------------------------------
__device__ __forceinline__ bool detect_f32(const u16* in, int tid, int* sflag) {
  if (tid < 64) {
    int cnt = 0;
#pragma unroll
    for (int j = 0; j < 8; j++) {
      u16 v = in[(tid * 8 + j) * 2];
      cnt += (((v >> 7) & 0xFF) >= 0xBF) ? 1 : 0;
    }
#pragma unroll
    for (int off = 1; off < 64; off <<= 1) cnt += __shfl_xor(cnt, off);
    if (tid == 0) *sflag = (cnt > 8) ? 1 : 0;
  }
  __syncthreads();
  return (*sflag != 0);
}

// ---------------------------------------------------------------------------
// Weight normalizer: all three matrices, 128 blocks each; converts fp32->bf16
// (or copies bf16). mat0/blk0 publishes the dtype flag for the epilogue.
// ---------------------------------------------------------------------------
__global__ __launch_bounds__(256) void conv3_kernel(
    const u16* __restrict__ w0, const u16* __restrict__ w1,
    const u16* __restrict__ w2, u16* __restrict__ o0,
    u16* __restrict__ o1, u16* __restrict__ o2, int* __restrict__ flag) {
  __shared__ int sflag;
  const int mat = blockIdx.x >> 7;
  const int blk = blockIdx.x & 127;
  const u16* in = (mat == 0) ? w0 : ((mat == 1) ? w1 : w2);
  u16* out = (mat == 0) ? o0 : ((mat == 1) ? o1 : o2);
  const int tid = threadIdx.x;
  const bool isf32 = detect_f32(in, tid, &sflag);
  if (tid == 0 && mat == 0 && blk == 0) *flag = isf32 ? 1 : 0;
  const size_t base = ((size_t)blk * 256 + tid) * 8;
  if (isf32) {
    const float* f = (const float*)in;
    us4 a, b;
#pragma unroll
    for (int j = 0; j < 4; j++) a[j] = f2bf(f[base + j]);
#pragma unroll
    for (int j = 0; j < 4; j++) b[j] = f2bf(f[base + 4 + j]);
    *(us4*)(out + base) = a;
    *(us4*)(out + base + 4) = b;
  } else {
    *(us8*)(out + base) = *(const us8*)(in + base);
  }
}

// ---------------------------------------------------------------------------
// QKV projection with fused x ingestion (fp32 or bf16 autodetected).
// grid (64 m-tiles, 3 mats), 4 waves. BM=64, BN=128, BK=64, dbuf LDS.
// Swizzled 16B chunks: LDS slot s=(r*W + cs) holds global chunk (r, cs^(r&7))
// -> frag ds_read_b128 at slot r*W + (cl^(r&7)) is 2-way-conflict (free).
// fp32 x path: reg-prefetch float4 loads + cvt + ds_write (global_load_lds
// can't convert); bf16 path + weights: async global->LDS, width 16.
// ---------------------------------------------------------------------------
__global__ __launch_bounds__(256, 2) void qkv_kernel(
    const u16* __restrict__ x, const u16* __restrict__ Wq,
    const u16* __restrict__ Wk, const u16* __restrict__ Wv,
    u16* __restrict__ Q, u16* __restrict__ K, u16* __restrict__ Vt)
{
  __shared__ __align__(16) u16 As[2][64 * 64];    // 2 x 8 KB
  __shared__ __align__(16) u16 Bs[2][128 * 64];   // 2 x 16 KB
  __shared__ int sflag;

  const int mat = blockIdx.y;
  const u16* W = (mat == 0) ? Wq : ((mat == 1) ? Wk : Wv);
  const int mtile = blockIdx.x;
  const int tid = threadIdx.x;
  const int wv = tid >> 6, lane = tid & 63, l15 = lane & 15, quad = lane >> 4;
  const int row0 = mtile * 64;

  const bool isf32 = detect_f32(x, tid, &sflag);

  f32x4 acc[8];
#pragma unroll
  for (int i = 0; i < 8; i++) acc[i] = (f32x4)0.0f;

  // my two A-chunks: slots 2*tid, 2*tid+1
  const int s0 = tid * 2;
  const int ar = s0 >> 3;                 // row 0..63
  const int ac0 = (s0 & 7) ^ (ar & 7);    // global chunk for slot s0
  const int ac1 = ((s0 + 1) & 7) ^ (ar & 7);

  f32x4 pa[4];                            // prefetched fp32 A data
  auto loadA_f32 = [&](int k0) {
    const float* xf = (const float*)x + (size_t)(row0 + ar) * D_IN + k0;
    pa[0] = *(const f32x4*)(xf + ac0 * 8);
    pa[1] = *(const f32x4*)(xf + ac0 * 8 + 4);
    pa[2] = *(const f32x4*)(xf + ac1 * 8);
    pa[3] = *(const f32x4*)(xf + ac1 * 8 + 4);
  };
  auto writeA_f32 = [&](int buf) {
    us8 c0, c1;
#pragma unroll
    for (int j = 0; j < 4; j++) {
      c0[j] = f2bf(pa[0][j]); c0[4 + j] = f2bf(pa[1][j]);
      c1[j] = f2bf(pa[2][j]); c1[4 + j] = f2bf(pa[3][j]);
    }
    *(us8*)((char*)As[buf] + (size_t)s0 * 16) = c0;
    *(us8*)((char*)As[buf] + (size_t)(s0 + 1) * 16) = c1;
  };
  auto stageA_bf16 = [&](int k0, int buf) {
#pragma unroll
    for (int j = 0; j < 2; j++) {
      int s = (wv * 2 + j) * 64 + lane;
      int r = s >> 3, cs = s & 7, c = cs ^ (r & 7);
      async_ld16(x + (size_t)(row0 + r) * D_IN + k0 + c * 8,
                 (char*)As[buf] + (size_t)(wv * 2 + j) * 1024);
    }
  };
  auto stageB = [&](int k0, int buf) {
#pragma unroll
    for (int j = 0; j < 4; j++) {
      int s = (wv * 4 + j) * 64 + lane;
      int n = s >> 3, cs = s & 7, c = cs ^ (n & 7);
      async_ld16(W + (size_t)n * D_IN + k0 + c * 8,
                 (char*)Bs[buf] + (size_t)(wv * 4 + j) * 1024);
    }
  };

  stageB(0, 0);
  if (isf32) loadA_f32(0); else stageA_bf16(0, 0);

  for (int kt = 0; kt < 32; kt++) {
    const int cur = kt & 1;
    if (isf32) writeA_f32(cur);          // A(kt) regs -> LDS cur
    __syncthreads();                     // drains A writes + B async for cur
    if (kt < 31) {                       // prefetch overlaps compute
      stageB((kt + 1) * 64, 1 - cur);
      if (isf32) loadA_f32((kt + 1) * 64); else stageA_bf16((kt + 1) * 64, 1 - cur);
    }
#pragma unroll
    for (int kc = 0; kc < 2; kc++) {
      const int rA = 16 * wv + l15;
      const int cl = kc * 4 + quad;
      bf16x8 a = *(const bf16x8*)((const char*)As[cur] + (rA * 8 + (cl ^ (rA & 7))) * 16);
#pragma unroll
      for (int nt = 0; nt < 8; nt++) {
        int n = 16 * nt + l15;
        bf16x8 b = *(const bf16x8*)((const char*)Bs[cur] + (n * 8 + (cl ^ (n & 7))) * 16);
        acc[nt] = __builtin_amdgcn_mfma_f32_16x16x32_bf16(a, b, acc[nt], 0, 0, 0);
      }
    }
  }

  // epilogue. D-frag: row = quad*4 + r, col = 16*nt + l15
  if (mat < 2) {
    u16* out = (mat == 0) ? Q : K;
#pragma unroll
    for (int nt = 0; nt < 8; nt++)
#pragma unroll
      for (int r = 0; r < 4; r++) {
        int m = row0 + 16 * wv + quad * 4 + r;
        int n = 16 * nt + l15;
        out[(size_t)m * HS + n] = f2bf(acc[nt][r]);
      }
  } else {
#pragma unroll
    for (int nt = 0; nt < 8; nt++) {
      int n = 16 * nt + l15;
      int mb = row0 + 16 * wv + quad * 4;
      us4 pk;
#pragma unroll
      for (int r = 0; r < 4; r++) pk[r] = f2bf(acc[nt][r]);
      *(us4*)(Vt + (size_t)n * T_TOK + mb) = pk;
    }
  }
}

// ---------------------------------------------------------------------------
// Split-KV flash attention. grid (64 qtiles, NCH chunks); block (qtile,ch)
// handles KV tiles [4ch, min(4ch+3, qtile)] and emits fp32 partial O + m,l.
// Dense slot index: slot(q,ch) = 64*ch - 2*ch*(ch-1) + (q - 4*ch).
// ---------------------------------------------------------------------------
__global__ __launch_bounds__(256, 2) void attn_split_kernel(
    const u16* __restrict__ Q, const u16* __restrict__ Kg,
    const u16* __restrict__ Vt, float* __restrict__ Opart,
    float* __restrict__ mstat, float* __restrict__ lstat)
{
  __shared__ __align__(16) u16 Ks[2][64 * 128];   // 2 x 16 KB
  __shared__ __align__(16) u16 Vs[2][128 * 64];   // 2 x 16 KB
  __shared__ __align__(16) u16 Ps[4 * 16 * 64];   // 8 KB (per-wave P)

  const int qtile = 63 - (int)blockIdx.x;         // heavy blocks first
  const int ch = blockIdx.y;
  if (4 * ch > qtile) return;
  const int t0 = 4 * ch;
  const int nsteps = min(CKV, qtile + 1 - t0);
  const int q0 = qtile * 64;
  const int slot = 64 * ch - 2 * ch * (ch - 1) + (qtile - 4 * ch);

  const int tid = threadIdx.x;
  const int wv = tid >> 6, lane = tid & 63, l15 = lane & 15, quad = lane >> 4;

  // Q A-frags: A[m=l15][k=quad*8+j]
  bf16x8 qf[4];
#pragma unroll
  for (int kc = 0; kc < 4; kc++)
    qf[kc] = *(const bf16x8*)(Q + (size_t)(q0 + 16 * wv + l15) * HS + kc * 32 + quad * 8);

  f32x4 o[8];
#pragma unroll
  for (int i = 0; i < 8; i++) o[i] = (f32x4)0.0f;
  float mrun[4], lrun[4];
#pragma unroll
  for (int r = 0; r < 4; r++) { mrun[r] = -1e30f; lrun[r] = 0.0f; }

  const float sc = 0.12752761571239668f; // log2(e)/sqrt(128)

  auto stage = [&](int t, int buf) {
#pragma unroll
    for (int j = 0; j < 4; j++) {
      int s = (wv * 4 + j) * 64 + lane;
      int n = s >> 4, cs = s & 15, c = cs ^ (n & 7);
      async_ld16(Kg + (size_t)(t * 64 + n) * HS + c * 8,
                 (char*)Ks[buf] + (size_t)(wv * 4 + j) * 1024);
    }
#pragma unroll
    for (int j = 0; j < 4; j++) {
      int s = (wv * 4 + j) * 64 + lane;
      int vr = s >> 3, cs = s & 7, c = cs ^ (vr & 7);
      async_ld16(Vt + (size_t)vr * T_TOK + t * 64 + c * 8,
                 (char*)Vs[buf] + (size_t)(wv * 4 + j) * 1024);
    }
  };

  stage(t0, 0);
  for (int i = 0; i < nsteps; i++) {
    const int cur = i & 1;
    const int t = t0 + i;
    __syncthreads();                           // drains loads for buf cur
    if (i + 1 < nsteps) stage(t + 1, 1 - cur); // prefetch overlaps compute

    // S = Q K^T
    f32x4 sacc[4];
#pragma unroll
    for (int nt = 0; nt < 4; nt++) sacc[nt] = (f32x4)0.0f;
#pragma unroll
    for (int kc = 0; kc < 4; kc++) {
      const int cl = kc * 4 + quad;
#pragma unroll
      for (int nt = 0; nt < 4; nt++) {
        int n = 16 * nt + l15;
        bf16x8 b = *(const bf16x8*)((const char*)Ks[cur] + (n * 16 + (cl ^ (n & 7))) * 16);
        sacc[nt] = __builtin_amdgcn_mfma_f32_16x16x32_bf16(qf[kc], b, sacc[nt], 0, 0, 0);
      }
    }

    // scale into log2 domain + causal mask (diagonal tile only)
    float s2[4][4];
    const bool diag = (t == qtile);
#pragma unroll
    for (int nt = 0; nt < 4; nt++)
#pragma unroll
      for (int r = 0; r < 4; r++) {
        float v = sacc[nt][r] * sc;
        if (diag) {
          int qr = q0 + 16 * wv + quad * 4 + r;
          int kr = t * 64 + 16 * nt + l15;
          if (kr > qr) v = -1e30f;
        }
        s2[nt][r] = v;
      }

    // online softmax; each row lives in the 16 lanes of one quad
    float mnew[4], alpha[4];
#pragma unroll
    for (int r = 0; r < 4; r++) {
      float tmax = fmaxf(fmaxf(s2[0][r], s2[1][r]), fmaxf(s2[2][r], s2[3][r]));
#pragma unroll
      for (int off = 1; off < 16; off <<= 1) tmax = fmaxf(tmax, __shfl_xor(tmax, off));
      mnew[r] = fmaxf(mrun[r], tmax);
      alpha[r] = exp2f(mrun[r] - mnew[r]);
      mrun[r] = mnew[r];
    }
    float p[4][4];
#pragma unroll
    for (int r = 0; r < 4; r++) {
      float s = 0.0f;
#pragma unroll
      for (int nt = 0; nt < 4; nt++) { p[nt][r] = exp2f(s2[nt][r] - mnew[r]); s += p[nt][r]; }
#pragma unroll
      for (int off = 1; off < 16; off <<= 1) s += __shfl_xor(s, off);
      lrun[r] = lrun[r] * alpha[r] + s;
    }
#pragma unroll
    for (int c = 0; c < 8; c++)
#pragma unroll
      for (int r = 0; r < 4; r++) o[c][r] *= alpha[r];

    // P: C-layout -> per-wave LDS (no barrier: DS in-order, Ps wave-private)
    u16* Pw = Ps + wv * 1024;
#pragma unroll
    for (int nt = 0; nt < 4; nt++)
#pragma unroll
      for (int r = 0; r < 4; r++) {
        int row = quad * 4 + r;
        int col = nt * 16 + l15;
        int cc = col >> 3, wi = col & 7;
        Pw[(row * 8 + (cc ^ (row & 7))) * 8 + wi] = f2bf(p[nt][r]);
      }

    // O += P V
#pragma unroll
    for (int kc = 0; kc < 2; kc++) {
      const int cl = kc * 4 + quad;
      bf16x8 a = *(const bf16x8*)((const char*)Pw + (l15 * 8 + (cl ^ (l15 & 7))) * 16);
#pragma unroll
      for (int c = 0; c < 8; c++) {
        int vr = 16 * c + l15;
        bf16x8 b = *(const bf16x8*)((const char*)Vs[cur] + (vr * 8 + (cl ^ (vr & 7))) * 16);
        o[c] = __builtin_amdgcn_mfma_f32_16x16x32_bf16(a, b, o[c], 0, 0, 0);
      }
    }
  }

  // store fp32 partial O + stats
  float* po = Opart + (size_t)slot * 64 * 128;
#pragma unroll
  for (int c = 0; c < 8; c++)
#pragma unroll
    for (int r = 0; r < 4; r++) {
      int ml = 16 * wv + quad * 4 + r;
      po[ml * 128 + 16 * c + l15] = o[c][r];
    }
  if (l15 == 0) {
#pragma unroll
    for (int r = 0; r < 4; r++) {
      int ml = 16 * wv + quad * 4 + r;
      mstat[slot * 64 + ml] = mrun[r];
      lstat[slot * 64 + ml] = lrun[r];
    }
  }
}

// ---------------------------------------------------------------------------
// Combine partials. grid (64 qtiles, 4 col-blocks), 256 threads.
// Thread handles one row x 8 cols. Output dtype per detected flag.
// ---------------------------------------------------------------------------
__global__ __launch_bounds__(256) void combine_kernel(
    const float* __restrict__ Opart, const float* __restrict__ mstat,
    const float* __restrict__ lstat, void* __restrict__ out_v,
    const int* __restrict__ dflag)
{
  const int q = blockIdx.x;
  const int cb = blockIdx.y;
  const int tid = threadIdx.x;
  const int row = tid >> 2;
  const int col = cb * 32 + (tid & 3) * 8;
  const int nch = (q + 4) / 4;   // ceil((q+1)/4)
  const bool of32 = (*dflag != 0);

  float M = -1e30f;
  {
    int base = 0;
    for (int c = 0; c < nch; c++) {
      int s = base + q - 4 * c;
      M = fmaxf(M, mstat[s * 64 + row]);
      base += 64 - 4 * c;
    }
  }
  float l = 0.0f;
  float acc[8];
#pragma unroll
  for (int j = 0; j < 8; j++) acc[j] = 0.0f;
  {
    int base = 0;
    for (int c = 0; c < nch; c++) {
      int s = base + q - 4 * c;
      float w = exp2f(mstat[s * 64 + row] - M);
      l += w * lstat[s * 64 + row];
      const float* op = Opart + ((size_t)s * 64 + row) * 128 + col;
      f32x4 a = *(const f32x4*)op;
      f32x4 b = *(const f32x4*)(op + 4);
#pragma unroll
      for (int j = 0; j < 4; j++) { acc[j] += w * a[j]; acc[4 + j] += w * b[j]; }
      base += 64 - 4 * c;
    }
  }
  const float inv = 1.0f / l;
  const size_t goff = (size_t)(q * 64 + row) * HS + col;
  if (of32) {
    float* out = (float*)out_v + goff;
    f32x4 r0, r1;
#pragma unroll
    for (int j = 0; j < 4; j++) { r0[j] = acc[j] * inv; r1[j] = acc[4 + j] * inv; }
    *(f32x4*)out = r0;
    *(f32x4*)(out + 4) = r1;
  } else {
    u16* out = (u16*)out_v + goff;
    us4 r0, r1;
#pragma unroll
    for (int j = 0; j < 4; j++) { r0[j] = f2bf(acc[j] * inv); r1[j] = f2bf(acc[4 + j] * inv); }
    *(us4*)out = r0;
    *(us4*)(out + 4) = r1;
  }
}

extern "C" void kernel_launch(void* const* d_in, const int* in_sizes, int n_in,
                              void* d_out, int out_size, void* d_ws, size_t ws_size,
                              hipStream_t stream) {
  const u16* x  = (const u16*)d_in[0];
  const u16* Wq = (const u16*)d_in[1];
  const u16* Wk = (const u16*)d_in[2];
  const u16* Wv = (const u16*)d_in[3];

  // ws layout (u16 units). The first region (partials) is written only by
  // attn_split, after qkv is done; Wb/Q/K/Vt live beyond it.
  float* Opart = (float*)d_ws;                   // 544 * 64*128 fp32 (17.8 MB)
  float* mstat = Opart + (size_t)544 * 64 * 128;
  float* lstat = mstat + (size_t)544 * 64;

  u16* Wqb = (u16*)(lstat + (size_t)544 * 64);   // 3 x 128*2048 bf16
  u16* Wkb = Wqb + (size_t)HS * D_IN;
  u16* Wvb = Wkb + (size_t)HS * D_IN;
  u16* Q   = Wvb + (size_t)HS * D_IN;            // 4096*128 bf16 each
  u16* K   = Q   + (size_t)T_TOK * HS;
  u16* Vt  = K   + (size_t)T_TOK * HS;
  int* flag = (int*)(Vt + (size_t)T_TOK * HS);

  conv3_kernel<<<384, 256, 0, stream>>>(Wq, Wk, Wv, Wqb, Wkb, Wvb, flag);
  qkv_kernel<<<dim3(64, 3), 256, 0, stream>>>(x, Wqb, Wkb, Wvb, Q, K, Vt);
  attn_split_kernel<<<dim3(64, NCH), 256, 0, stream>>>(Q, K, Vt, Opart, mstat, lstat);
  combine_kernel<<<dim3(64, 4), 256, 0, stream>>>(Opart, mstat, lstat, d_out, flag);
}

// Round 8
// 139.460 us; speedup vs baseline: 1.7709x; 1.0583x over previous
//
#include <hip/hip_runtime.h>
#include <hip/hip_bf16.h>

#define T_TOK 4096
#define D_IN  2048
#define HS    128
#define CKV   4      // KV tiles per attention chunk
#define NCH   16     // ceil(64 / CKV)

typedef unsigned short u16;
typedef __attribute__((ext_vector_type(8))) __bf16 bf16x8;
typedef __attribute__((ext_vector_type(4))) float f32x4;
typedef __attribute__((ext_vector_type(4))) unsigned short us4;
typedef __attribute__((ext_vector_type(8))) unsigned short us8;

#define GLOBAL_AS __attribute__((address_space(1)))
#define LDS_AS    __attribute__((address_space(3)))

__device__ __forceinline__ void async_ld16(const void* g, void* l) {
  __builtin_amdgcn_global_load_lds((GLOBAL_AS void*)(void*)g, (LDS_AS void*)l, 16, 0, 0);
}

__device__ __forceinline__ u16 f2bf(float v) {
  return __builtin_bit_cast(u16, __float2bfloat16(v));
}

// ---------------------------------------------------------------------------
// fp32-vs-bf16 autodetect on a buffer head: even u16s of fp32 data are raw
// low-mantissa bits -> ~25% have "exponent" field >= 0xBF; genuine bf16
// N(0,s) has none. Returns wave-uniform flag via LDS broadcast.
// ---------------------------------------------------------------------------
__device__ __forceinline__ bool detect_f32(const u16* in, int tid, int* sflag) {
  if (tid < 64) {
    int cnt = 0;
#pragma unroll
    for (int j = 0; j < 8; j++) {
      u16 v = in[(tid * 8 + j) * 2];
      cnt += (((v >> 7) & 0xFF) >= 0xBF) ? 1 : 0;
    }
#pragma unroll
    for (int off = 1; off < 64; off <<= 1) cnt += __shfl_xor(cnt, off);
    if (tid == 0) *sflag = (cnt > 8) ? 1 : 0;
  }
  __syncthreads();
  return (*sflag != 0);
}

// ---------------------------------------------------------------------------
// Weight normalizer: all three matrices, 128 blocks each; converts fp32->bf16
// (or copies bf16). mat0/blk0 publishes the dtype flag for the epilogue.
// ---------------------------------------------------------------------------
__global__ __launch_bounds__(256) void conv3_kernel(
    const u16* __restrict__ w0, const u16* __restrict__ w1,
    const u16* __restrict__ w2, u16* __restrict__ o0,
    u16* __restrict__ o1, u16* __restrict__ o2, int* __restrict__ flag) {
  __shared__ int sflag;
  const int mat = blockIdx.x >> 7;
  const int blk = blockIdx.x & 127;
  const u16* in = (mat == 0) ? w0 : ((mat == 1) ? w1 : w2);
  u16* out = (mat == 0) ? o0 : ((mat == 1) ? o1 : o2);
  const int tid = threadIdx.x;
  const bool isf32 = detect_f32(in, tid, &sflag);
  if (tid == 0 && mat == 0 && blk == 0) *flag = isf32 ? 1 : 0;
  const size_t base = ((size_t)blk * 256 + tid) * 8;
  if (isf32) {
    const float* f = (const float*)in;
    us4 a, b;
#pragma unroll
    for (int j = 0; j < 4; j++) a[j] = f2bf(f[base + j]);
#pragma unroll
    for (int j = 0; j < 4; j++) b[j] = f2bf(f[base + 4 + j]);
    *(us4*)(out + base) = a;
    *(us4*)(out + base + 4) = b;
  } else {
    *(us8*)(out + base) = *(const us8*)(in + base);
  }
}

// ---------------------------------------------------------------------------
// QKV projection v2: BM=32 for occupancy. grid (128 m-tiles, 3 mats), 4 waves.
// Wave wv: row band = wv&1 (16 rows), col half = wv>>1 (64 of 128 cols).
// BK=64, dbuf LDS = 40 KB -> up to 3 blocks/CU co-resident; inter-block
// overlap hides the per-iteration barrier drain (round-7 diagnosis: 1
// block/CU left every pipe ~95% idle).
// Swizzled 16B chunks: chunk (row r, c) at slot r*8 + (c ^ (r&7)).
// fp32 x path: reg-prefetch float4 + cvt + ds_write; bf16 path + W: async.
// ---------------------------------------------------------------------------
__global__ __launch_bounds__(256, 2) void qkv_kernel(
    const u16* __restrict__ x, const u16* __restrict__ Wq,
    const u16* __restrict__ Wk, const u16* __restrict__ Wv,
    u16* __restrict__ Q, u16* __restrict__ K, u16* __restrict__ Vt)
{
  __shared__ __align__(16) u16 As[2][32 * 64];    // 2 x 4 KB
  __shared__ __align__(16) u16 Bs[2][128 * 64];   // 2 x 16 KB
  __shared__ int sflag;

  const int mat = blockIdx.y;
  const u16* W = (mat == 0) ? Wq : ((mat == 1) ? Wk : Wv);
  const int mtile = blockIdx.x;
  const int tid = threadIdx.x;
  const int wv = tid >> 6, lane = tid & 63, l15 = lane & 15, quad = lane >> 4;
  const int rband = wv & 1, chalf = wv >> 1;
  const int row0 = mtile * 32;

  const bool isf32 = detect_f32(x, tid, &sflag);

  f32x4 acc[4];
#pragma unroll
  for (int i = 0; i < 4; i++) acc[i] = (f32x4)0.0f;

  // A: 32x64 bf16 = 256 chunks, 8/row; 1 chunk per thread (slot = tid)
  const int ar = tid >> 3;                 // row 0..31
  const int ac = (tid & 7) ^ (ar & 7);     // global chunk for my slot

  f32x4 pa[2];                             // prefetched fp32 A data
  auto loadA_f32 = [&](int k0) {
    const float* xf = (const float*)x + (size_t)(row0 + ar) * D_IN + k0;
    pa[0] = *(const f32x4*)(xf + ac * 8);
    pa[1] = *(const f32x4*)(xf + ac * 8 + 4);
  };
  auto writeA_f32 = [&](int buf) {
    us8 c0;
#pragma unroll
    for (int j = 0; j < 4; j++) { c0[j] = f2bf(pa[0][j]); c0[4 + j] = f2bf(pa[1][j]); }
    *(us8*)((char*)As[buf] + (size_t)tid * 16) = c0;
  };
  auto stageA_bf16 = [&](int k0, int buf) {
    // per wave: slots wv*64+lane -> base wv*1024 + lane*16 (wave-uniform base)
    async_ld16(x + (size_t)(row0 + ar) * D_IN + k0 + ac * 8,
               (char*)As[buf] + (size_t)wv * 1024);
  };
  auto stageB = [&](int k0, int buf) {
#pragma unroll
    for (int j = 0; j < 4; j++) {
      int s = (wv * 4 + j) * 64 + lane;
      int n = s >> 3, cs = s & 7, c = cs ^ (n & 7);
      async_ld16(W + (size_t)n * D_IN + k0 + c * 8,
                 (char*)Bs[buf] + (size_t)(wv * 4 + j) * 1024);
    }
  };

  stageB(0, 0);
  if (isf32) loadA_f32(0); else stageA_bf16(0, 0);

  for (int kt = 0; kt < 32; kt++) {
    const int cur = kt & 1;
    if (isf32) writeA_f32(cur);          // A(kt) regs -> LDS cur
    __syncthreads();                     // drains A writes + async for cur
    if (kt < 31) {                       // prefetch overlaps compute
      stageB((kt + 1) * 64, 1 - cur);
      if (isf32) loadA_f32((kt + 1) * 64); else stageA_bf16((kt + 1) * 64, 1 - cur);
    }
#pragma unroll
    for (int kc = 0; kc < 2; kc++) {
      const int rA = 16 * rband + l15;
      const int cl = kc * 4 + quad;
      bf16x8 a = *(const bf16x8*)((const char*)As[cur] + (rA * 8 + (cl ^ (rA & 7))) * 16);
#pragma unroll
      for (int nt = 0; nt < 4; nt++) {
        int n = chalf * 64 + 16 * nt + l15;
        bf16x8 b = *(const bf16x8*)((const char*)Bs[cur] + (n * 8 + (cl ^ (n & 7))) * 16);
        acc[nt] = __builtin_amdgcn_mfma_f32_16x16x32_bf16(a, b, acc[nt], 0, 0, 0);
      }
    }
  }

  // epilogue. D-frag: row = quad*4 + r, col = 16*nt + l15 (within wave tile)
  if (mat < 2) {
    u16* out = (mat == 0) ? Q : K;
#pragma unroll
    for (int nt = 0; nt < 4; nt++)
#pragma unroll
      for (int r = 0; r < 4; r++) {
        int m = row0 + 16 * rband + quad * 4 + r;
        int n = chalf * 64 + 16 * nt + l15;
        out[(size_t)m * HS + n] = f2bf(acc[nt][r]);
      }
  } else {
#pragma unroll
    for (int nt = 0; nt < 4; nt++) {
      int n = chalf * 64 + 16 * nt + l15;
      int mb = row0 + 16 * rband + quad * 4;
      us4 pk;
#pragma unroll
      for (int r = 0; r < 4; r++) pk[r] = f2bf(acc[nt][r]);
      *(us4*)(Vt + (size_t)n * T_TOK + mb) = pk;
    }
  }
}

// ---------------------------------------------------------------------------
// Split-KV flash attention. grid (64 qtiles, NCH chunks); block (qtile,ch)
// handles KV tiles [4ch, min(4ch+3, qtile)] and emits fp32 partial O + m,l.
// Dense slot index: slot(q,ch) = 64*ch - 2*ch*(ch-1) + (q - 4*ch).
// ---------------------------------------------------------------------------
__global__ __launch_bounds__(256, 2) void attn_split_kernel(
    const u16* __restrict__ Q, const u16* __restrict__ Kg,
    const u16* __restrict__ Vt, float* __restrict__ Opart,
    float* __restrict__ mstat, float* __restrict__ lstat)
{
  __shared__ __align__(16) u16 Ks[2][64 * 128];   // 2 x 16 KB
  __shared__ __align__(16) u16 Vs[2][128 * 64];   // 2 x 16 KB
  __shared__ __align__(16) u16 Ps[4 * 16 * 64];   // 8 KB (per-wave P)

  const int qtile = 63 - (int)blockIdx.x;         // heavy blocks first
  const int ch = blockIdx.y;
  if (4 * ch > qtile) return;
  const int t0 = 4 * ch;
  const int nsteps = min(CKV, qtile + 1 - t0);
  const int q0 = qtile * 64;
  const int slot = 64 * ch - 2 * ch * (ch - 1) + (qtile - 4 * ch);

  const int tid = threadIdx.x;
  const int wv = tid >> 6, lane = tid & 63, l15 = lane & 15, quad = lane >> 4;

  // Q A-frags: A[m=l15][k=quad*8+j]
  bf16x8 qf[4];
#pragma unroll
  for (int kc = 0; kc < 4; kc++)
    qf[kc] = *(const bf16x8*)(Q + (size_t)(q0 + 16 * wv + l15) * HS + kc * 32 + quad * 8);

  f32x4 o[8];
#pragma unroll
  for (int i = 0; i < 8; i++) o[i] = (f32x4)0.0f;
  float mrun[4], lrun[4];
#pragma unroll
  for (int r = 0; r < 4; r++) { mrun[r] = -1e30f; lrun[r] = 0.0f; }

  const float sc = 0.12752761571239668f; // log2(e)/sqrt(128)

  auto stage = [&](int t, int buf) {
#pragma unroll
    for (int j = 0; j < 4; j++) {
      int s = (wv * 4 + j) * 64 + lane;
      int n = s >> 4, cs = s & 15, c = cs ^ (n & 7);
      async_ld16(Kg + (size_t)(t * 64 + n) * HS + c * 8,
                 (char*)Ks[buf] + (size_t)(wv * 4 + j) * 1024);
    }
#pragma unroll
    for (int j = 0; j < 4; j++) {
      int s = (wv * 4 + j) * 64 + lane;
      int vr = s >> 3, cs = s & 7, c = cs ^ (vr & 7);
      async_ld16(Vt + (size_t)vr * T_TOK + t * 64 + c * 8,
                 (char*)Vs[buf] + (size_t)(wv * 4 + j) * 1024);
    }
  };

  stage(t0, 0);
  for (int i = 0; i < nsteps; i++) {
    const int cur = i & 1;
    const int t = t0 + i;
    __syncthreads();                           // drains loads for buf cur
    if (i + 1 < nsteps) stage(t + 1, 1 - cur); // prefetch overlaps compute

    // S = Q K^T
    f32x4 sacc[4];
#pragma unroll
    for (int nt = 0; nt < 4; nt++) sacc[nt] = (f32x4)0.0f;
#pragma unroll
    for (int kc = 0; kc < 4; kc++) {
      const int cl = kc * 4 + quad;
#pragma unroll
      for (int nt = 0; nt < 4; nt++) {
        int n = 16 * nt + l15;
        bf16x8 b = *(const bf16x8*)((const char*)Ks[cur] + (n * 16 + (cl ^ (n & 7))) * 16);
        sacc[nt] = __builtin_amdgcn_mfma_f32_16x16x32_bf16(qf[kc], b, sacc[nt], 0, 0, 0);
      }
    }

    // scale into log2 domain + causal mask (diagonal tile only)
    float s2[4][4];
    const bool diag = (t == qtile);
#pragma unroll
    for (int nt = 0; nt < 4; nt++)
#pragma unroll
      for (int r = 0; r < 4; r++) {
        float v = sacc[nt][r] * sc;
        if (diag) {
          int qr = q0 + 16 * wv + quad * 4 + r;
          int kr = t * 64 + 16 * nt + l15;
          if (kr > qr) v = -1e30f;
        }
        s2[nt][r] = v;
      }

    // online softmax; each row lives in the 16 lanes of one quad
    float mnew[4], alpha[4];
#pragma unroll
    for (int r = 0; r < 4; r++) {
      float tmax = fmaxf(fmaxf(s2[0][r], s2[1][r]), fmaxf(s2[2][r], s2[3][r]));
#pragma unroll
      for (int off = 1; off < 16; off <<= 1) tmax = fmaxf(tmax, __shfl_xor(tmax, off));
      mnew[r] = fmaxf(mrun[r], tmax);
      alpha[r] = exp2f(mrun[r] - mnew[r]);
      mrun[r] = mnew[r];
    }
    float p[4][4];
#pragma unroll
    for (int r = 0; r < 4; r++) {
      float s = 0.0f;
#pragma unroll
      for (int nt = 0; nt < 4; nt++) { p[nt][r] = exp2f(s2[nt][r] - mnew[r]); s += p[nt][r]; }
#pragma unroll
      for (int off = 1; off < 16; off <<= 1) s += __shfl_xor(s, off);
      lrun[r] = lrun[r] * alpha[r] + s;
    }
#pragma unroll
    for (int c = 0; c < 8; c++)
#pragma unroll
      for (int r = 0; r < 4; r++) o[c][r] *= alpha[r];

    // P: C-layout -> per-wave LDS (no barrier: DS in-order, Ps wave-private)
    u16* Pw = Ps + wv * 1024;
#pragma unroll
    for (int nt = 0; nt < 4; nt++)
#pragma unroll
      for (int r = 0; r < 4; r++) {
        int row = quad * 4 + r;
        int col = nt * 16 + l15;
        int cc = col >> 3, wi = col & 7;
        Pw[(row * 8 + (cc ^ (row & 7))) * 8 + wi] = f2bf(p[nt][r]);
      }

    // O += P V
#pragma unroll
    for (int kc = 0; kc < 2; kc++) {
      const int cl = kc * 4 + quad;
      bf16x8 a = *(const bf16x8*)((const char*)Pw + (l15 * 8 + (cl ^ (l15 & 7))) * 16);
#pragma unroll
      for (int c = 0; c < 8; c++) {
        int vr = 16 * c + l15;
        bf16x8 b = *(const bf16x8*)((const char*)Vs[cur] + (vr * 8 + (cl ^ (vr & 7))) * 16);
        o[c] = __builtin_amdgcn_mfma_f32_16x16x32_bf16(a, b, o[c], 0, 0, 0);
      }
    }
  }

  // store fp32 partial O + stats
  float* po = Opart + (size_t)slot * 64 * 128;
#pragma unroll
  for (int c = 0; c < 8; c++)
#pragma unroll
    for (int r = 0; r < 4; r++) {
      int ml = 16 * wv + quad * 4 + r;
      po[ml * 128 + 16 * c + l15] = o[c][r];
    }
  if (l15 == 0) {
#pragma unroll
    for (int r = 0; r < 4; r++) {
      int ml = 16 * wv + quad * 4 + r;
      mstat[slot * 64 + ml] = mrun[r];
      lstat[slot * 64 + ml] = lrun[r];
    }
  }
}

// ---------------------------------------------------------------------------
// Combine partials. grid (64 qtiles, 4 col-blocks), 256 threads.
// Thread handles one row x 8 cols. Output dtype per detected flag.
// ---------------------------------------------------------------------------
__global__ __launch_bounds__(256) void combine_kernel(
    const float* __restrict__ Opart, const float* __restrict__ mstat,
    const float* __restrict__ lstat, void* __restrict__ out_v,
    const int* __restrict__ dflag)
{
  const int q = blockIdx.x;
  const int cb = blockIdx.y;
  const int tid = threadIdx.x;
  const int row = tid >> 2;
  const int col = cb * 32 + (tid & 3) * 8;
  const int nch = (q + 4) / 4;   // ceil((q+1)/4)
  const bool of32 = (*dflag != 0);

  float M = -1e30f;
  {
    int base = 0;
    for (int c = 0; c < nch; c++) {
      int s = base + q - 4 * c;
      M = fmaxf(M, mstat[s * 64 + row]);
      base += 64 - 4 * c;
    }
  }
  float l = 0.0f;
  float acc[8];
#pragma unroll
  for (int j = 0; j < 8; j++) acc[j] = 0.0f;
  {
    int base = 0;
    for (int c = 0; c < nch; c++) {
      int s = base + q - 4 * c;
      float w = exp2f(mstat[s * 64 + row] - M);
      l += w * lstat[s * 64 + row];
      const float* op = Opart + ((size_t)s * 64 + row) * 128 + col;
      f32x4 a = *(const f32x4*)op;
      f32x4 b = *(const f32x4*)(op + 4);
#pragma unroll
      for (int j = 0; j < 4; j++) { acc[j] += w * a[j]; acc[4 + j] += w * b[j]; }
      base += 64 - 4 * c;
    }
  }
  const float inv = 1.0f / l;
  const size_t goff = (size_t)(q * 64 + row) * HS + col;
  if (of32) {
    float* out = (float*)out_v + goff;
    f32x4 r0, r1;
#pragma unroll
    for (int j = 0; j < 4; j++) { r0[j] = acc[j] * inv; r1[j] = acc[4 + j] * inv; }
    *(f32x4*)out = r0;
    *(f32x4*)(out + 4) = r1;
  } else {
    u16* out = (u16*)out_v + goff;
    us4 r0, r1;
#pragma unroll
    for (int j = 0; j < 4; j++) { r0[j] = f2bf(acc[j] * inv); r1[j] = f2bf(acc[4 + j] * inv); }
    *(us4*)out = r0;
    *(us4*)(out + 4) = r1;
  }
}

extern "C" void kernel_launch(void* const* d_in, const int* in_sizes, int n_in,
                              void* d_out, int out_size, void* d_ws, size_t ws_size,
                              hipStream_t stream) {
  const u16* x  = (const u16*)d_in[0];
  const u16* Wq = (const u16*)d_in[1];
  const u16* Wk = (const u16*)d_in[2];
  const u16* Wv = (const u16*)d_in[3];

  // ws layout (u16 units). The first region (partials) is written only by
  // attn_split, after qkv is done; Wb/Q/K/Vt live beyond it.
  float* Opart = (float*)d_ws;                   // 544 * 64*128 fp32 (17.8 MB)
  float* mstat = Opart + (size_t)544 * 64 * 128;
  float* lstat = mstat + (size_t)544 * 64;

  u16* Wqb = (u16*)(lstat + (size_t)544 * 64);   // 3 x 128*2048 bf16
  u16* Wkb = Wqb + (size_t)HS * D_IN;
  u16* Wvb = Wkb + (size_t)HS * D_IN;
  u16* Q   = Wvb + (size_t)HS * D_IN;            // 4096*128 bf16 each
  u16* K   = Q   + (size_t)T_TOK * HS;
  u16* Vt  = K   + (size_t)T_TOK * HS;
  int* flag = (int*)(Vt + (size_t)T_TOK * HS);

  conv3_kernel<<<384, 256, 0, stream>>>(Wq, Wk, Wv, Wqb, Wkb, Wvb, flag);
  qkv_kernel<<<dim3(128, 3), 256, 0, stream>>>(x, Wqb, Wkb, Wvb, Q, K, Vt);
  attn_split_kernel<<<dim3(64, NCH), 256, 0, stream>>>(Q, K, Vt, Opart, mstat, lstat);
  combine_kernel<<<dim3(64, 4), 256, 0, stream>>>(Opart, mstat, lstat, d_out, flag);
}

// Round 10
// 137.763 us; speedup vs baseline: 1.7927x; 1.0123x over previous
//
#include <hip/hip_runtime.h>
#include <hip/hip_bf16.h>

#define T_TOK 4096
#define D_IN  2048
#define HS    128
#define CKV   4      // KV tiles per attention chunk
#define NCH   16     // ceil(64 / CKV)

typedef unsigned short u16;
typedef __attribute__((ext_vector_type(8))) __bf16 bf16x8;
typedef __attribute__((ext_vector_type(4))) float f32x4;
typedef __attribute__((ext_vector_type(4))) unsigned short us4;
typedef __attribute__((ext_vector_type(8))) unsigned short us8;

#define GLOBAL_AS __attribute__((address_space(1)))
#define LDS_AS    __attribute__((address_space(3)))

__device__ __forceinline__ void async_ld16(const void* g, void* l) {
  __builtin_amdgcn_global_load_lds((GLOBAL_AS void*)(void*)g, (LDS_AS void*)l, 16, 0, 0);
}

__device__ __forceinline__ u16 f2bf(float v) {
  return __builtin_bit_cast(u16, __float2bfloat16(v));
}

// ---------------------------------------------------------------------------
// fp32-vs-bf16 autodetect on a buffer head: even u16s of fp32 data are raw
// low-mantissa bits -> ~25% have "exponent" field >= 0xBF; genuine bf16
// N(0,s) has none. Returns wave-uniform flag via LDS broadcast.
// ---------------------------------------------------------------------------
__device__ __forceinline__ bool detect_f32(const u16* in, int tid, int* sflag) {
  if (tid < 64) {
    int cnt = 0;
#pragma unroll
    for (int j = 0; j < 8; j++) {
      u16 v = in[(tid * 8 + j) * 2];
      cnt += (((v >> 7) & 0xFF) >= 0xBF) ? 1 : 0;
    }
#pragma unroll
    for (int off = 1; off < 64; off <<= 1) cnt += __shfl_xor(cnt, off);
    if (tid == 0) *sflag = (cnt > 8) ? 1 : 0;
  }
  __syncthreads();
  return (*sflag != 0);
}

// ---------------------------------------------------------------------------
// Weight normalizer: all three matrices, 128 blocks each; converts fp32->bf16
// (or copies bf16). mat0/blk0 publishes the dtype flag for the epilogue.
// ---------------------------------------------------------------------------
__global__ __launch_bounds__(256) void conv3_kernel(
    const u16* __restrict__ w0, const u16* __restrict__ w1,
    const u16* __restrict__ w2, u16* __restrict__ o0,
    u16* __restrict__ o1, u16* __restrict__ o2, int* __restrict__ flag) {
  __shared__ int sflag;
  const int mat = blockIdx.x >> 7;
  const int blk = blockIdx.x & 127;
  const u16* in = (mat == 0) ? w0 : ((mat == 1) ? w1 : w2);
  u16* out = (mat == 0) ? o0 : ((mat == 1) ? o1 : o2);
  const int tid = threadIdx.x;
  const bool isf32 = detect_f32(in, tid, &sflag);
  if (tid == 0 && mat == 0 && blk == 0) *flag = isf32 ? 1 : 0;
  const size_t base = ((size_t)blk * 256 + tid) * 8;
  if (isf32) {
    const float* f = (const float*)in;
    us4 a, b;
#pragma unroll
    for (int j = 0; j < 4; j++) a[j] = f2bf(f[base + j]);
#pragma unroll
    for (int j = 0; j < 4; j++) b[j] = f2bf(f[base + 4 + j]);
    *(us4*)(out + base) = a;
    *(us4*)(out + base + 4) = b;
  } else {
    *(us8*)(out + base) = *(const us8*)(in + base);
  }
}

// ---------------------------------------------------------------------------
// QKV projection v3: BM=16. grid (256 m-tiles, 3 mats) = 768 blocks -> ~3
// blocks/CU co-resident (round-8 diagnosis: 384 blocks = 1.5/CU left the
// per-iteration barrier drain exposed; LDS allowed 4/CU, grid didn't).
// 4 waves: all share the 16 A-rows; wave wv covers cols [32wv, 32wv+32).
// LDS 36 KB: A 2x2 KB + B 2x16 KB, double-buffered, BK=64.
// Swizzled 16B chunks: chunk (row r, c) at slot r*8 + (c ^ (r&7)).
// fp32 x path: reg-prefetch float4 + cvt + ds_write (threads 0..127);
// bf16 x path: waves 0-1 issue global_load_lds. Weights: async, all waves.
// ---------------------------------------------------------------------------
__global__ __launch_bounds__(256, 2) void qkv_kernel(
    const u16* __restrict__ x, const u16* __restrict__ Wq,
    const u16* __restrict__ Wk, const u16* __restrict__ Wv,
    u16* __restrict__ Q, u16* __restrict__ K, u16* __restrict__ Vt)
{
  __shared__ __align__(16) u16 As[2][16 * 64];    // 2 x 2 KB
  __shared__ __align__(16) u16 Bs[2][128 * 64];   // 2 x 16 KB
  __shared__ int sflag;

  const int mat = blockIdx.y;
  const u16* W = (mat == 0) ? Wq : ((mat == 1) ? Wk : Wv);
  const int mtile = blockIdx.x;
  const int tid = threadIdx.x;
  const int wv = tid >> 6, lane = tid & 63, l15 = lane & 15, quad = lane >> 4;
  const int row0 = mtile * 16;

  const bool isf32 = detect_f32(x, tid, &sflag);

  f32x4 acc[2];
#pragma unroll
  for (int i = 0; i < 2; i++) acc[i] = (f32x4)0.0f;

  // A: 16x64 bf16 = 128 chunks of 16B, 8/row; threads 0..127 own slot tid
  const int ar = tid >> 3;                 // row 0..15 (tid<128)
  const int ac = (tid & 7) ^ (ar & 7);     // global chunk for my slot

  f32x4 pa[2];                             // prefetched fp32 A data
  auto loadA_f32 = [&](int k0) {
    if (tid < 128) {
      const float* xf = (const float*)x + (size_t)(row0 + ar) * D_IN + k0;
      pa[0] = *(const f32x4*)(xf + ac * 8);
      pa[1] = *(const f32x4*)(xf + ac * 8 + 4);
    }
  };
  auto writeA_f32 = [&](int buf) {
    if (tid < 128) {
      us8 c0;
#pragma unroll
      for (int j = 0; j < 4; j++) { c0[j] = f2bf(pa[0][j]); c0[4 + j] = f2bf(pa[1][j]); }
      *(us8*)((char*)As[buf] + (size_t)tid * 16) = c0;
    }
  };
  auto stageA_bf16 = [&](int k0, int buf) {
    if (wv < 2) {   // wave-uniform branch; waves 0-1 cover the 128 chunks
      async_ld16(x + (size_t)(row0 + ar) * D_IN + k0 + ac * 8,
                 (char*)As[buf] + (size_t)wv * 1024);
    }
  };
  auto stageB = [&](int k0, int buf) {
#pragma unroll
    for (int j = 0; j < 4; j++) {
      int s = (wv * 4 + j) * 64 + lane;
      int n = s >> 3, cs = s & 7, c = cs ^ (n & 7);
      async_ld16(W + (size_t)n * D_IN + k0 + c * 8,
                 (char*)Bs[buf] + (size_t)(wv * 4 + j) * 1024);
    }
  };

  stageB(0, 0);
  if (isf32) loadA_f32(0); else stageA_bf16(0, 0);

  for (int kt = 0; kt < 32; kt++) {
    const int cur = kt & 1;
    if (isf32) writeA_f32(cur);          // A(kt) regs -> LDS cur
    __syncthreads();                     // drains A writes + async for cur
    if (kt < 31) {                       // prefetch overlaps compute
      stageB((kt + 1) * 64, 1 - cur);
      if (isf32) loadA_f32((kt + 1) * 64); else stageA_bf16((kt + 1) * 64, 1 - cur);
    }
#pragma unroll
    for (int kc = 0; kc < 2; kc++) {
      const int rA = l15;
      const int cl = kc * 4 + quad;
      bf16x8 a = *(const bf16x8*)((const char*)As[cur] + (rA * 8 + (cl ^ (rA & 7))) * 16);
#pragma unroll
      for (int nt = 0; nt < 2; nt++) {
        int n = wv * 32 + 16 * nt + l15;
        bf16x8 b = *(const bf16x8*)((const char*)Bs[cur] + (n * 8 + (cl ^ (n & 7))) * 16);
        acc[nt] = __builtin_amdgcn_mfma_f32_16x16x32_bf16(a, b, acc[nt], 0, 0, 0);
      }
    }
  }

  // epilogue. D-frag: row = quad*4 + r, col = 16*nt + l15 (within wave cols)
  if (mat < 2) {
    u16* out = (mat == 0) ? Q : K;
#pragma unroll
    for (int nt = 0; nt < 2; nt++)
#pragma unroll
      for (int r = 0; r < 4; r++) {
        int m = row0 + quad * 4 + r;
        int n = wv * 32 + 16 * nt + l15;
        out[(size_t)m * HS + n] = f2bf(acc[nt][r]);
      }
  } else {
#pragma unroll
    for (int nt = 0; nt < 2; nt++) {
      int n = wv * 32 + 16 * nt + l15;
      int mb = row0 + quad * 4;
      us4 pk;
#pragma unroll
      for (int r = 0; r < 4; r++) pk[r] = f2bf(acc[nt][r]);
      *(us4*)(Vt + (size_t)n * T_TOK + mb) = pk;
    }
  }
}

// ---------------------------------------------------------------------------
// Split-KV flash attention. grid (64 qtiles, NCH chunks); block (qtile,ch)
// handles KV tiles [4ch, min(4ch+3, qtile)] and emits fp32 partial O + m,l.
// Dense slot index: slot(q,ch) = 64*ch - 2*ch*(ch-1) + (q - 4*ch).
// ---------------------------------------------------------------------------
__global__ __launch_bounds__(256, 2) void attn_split_kernel(
    const u16* __restrict__ Q, const u16* __restrict__ Kg,
    const u16* __restrict__ Vt, float* __restrict__ Opart,
    float* __restrict__ mstat, float* __restrict__ lstat)
{
  __shared__ __align__(16) u16 Ks[2][64 * 128];   // 2 x 16 KB
  __shared__ __align__(16) u16 Vs[2][128 * 64];   // 2 x 16 KB
  __shared__ __align__(16) u16 Ps[4 * 16 * 64];   // 8 KB (per-wave P)

  const int qtile = 63 - (int)blockIdx.x;         // heavy blocks first
  const int ch = blockIdx.y;
  if (4 * ch > qtile) return;
  const int t0 = 4 * ch;
  const int nsteps = min(CKV, qtile + 1 - t0);
  const int q0 = qtile * 64;
  const int slot = 64 * ch - 2 * ch * (ch - 1) + (qtile - 4 * ch);

  const int tid = threadIdx.x;
  const int wv = tid >> 6, lane = tid & 63, l15 = lane & 15, quad = lane >> 4;

  // Q A-frags: A[m=l15][k=quad*8+j]
  bf16x8 qf[4];
#pragma unroll
  for (int kc = 0; kc < 4; kc++)
    qf[kc] = *(const bf16x8*)(Q + (size_t)(q0 + 16 * wv + l15) * HS + kc * 32 + quad * 8);

  f32x4 o[8];
#pragma unroll
  for (int i = 0; i < 8; i++) o[i] = (f32x4)0.0f;
  float mrun[4], lrun[4];
#pragma unroll
  for (int r = 0; r < 4; r++) { mrun[r] = -1e30f; lrun[r] = 0.0f; }

  const float sc = 0.12752761571239668f; // log2(e)/sqrt(128)

  auto stage = [&](int t, int buf) {
#pragma unroll
    for (int j = 0; j < 4; j++) {
      int s = (wv * 4 + j) * 64 + lane;
      int n = s >> 4, cs = s & 15, c = cs ^ (n & 7);
      async_ld16(Kg + (size_t)(t * 64 + n) * HS + c * 8,
                 (char*)Ks[buf] + (size_t)(wv * 4 + j) * 1024);
    }
#pragma unroll
    for (int j = 0; j < 4; j++) {
      int s = (wv * 4 + j) * 64 + lane;
      int vr = s >> 3, cs = s & 7, c = cs ^ (vr & 7);
      async_ld16(Vt + (size_t)vr * T_TOK + t * 64 + c * 8,
                 (char*)Vs[buf] + (size_t)(wv * 4 + j) * 1024);
    }
  };

  stage(t0, 0);
  for (int i = 0; i < nsteps; i++) {
    const int cur = i & 1;
    const int t = t0 + i;
    __syncthreads();                           // drains loads for buf cur
    if (i + 1 < nsteps) stage(t + 1, 1 - cur); // prefetch overlaps compute

    // S = Q K^T
    f32x4 sacc[4];
#pragma unroll
    for (int nt = 0; nt < 4; nt++) sacc[nt] = (f32x4)0.0f;
#pragma unroll
    for (int kc = 0; kc < 4; kc++) {
      const int cl = kc * 4 + quad;
#pragma unroll
      for (int nt = 0; nt < 4; nt++) {
        int n = 16 * nt + l15;
        bf16x8 b = *(const bf16x8*)((const char*)Ks[cur] + (n * 16 + (cl ^ (n & 7))) * 16);
        sacc[nt] = __builtin_amdgcn_mfma_f32_16x16x32_bf16(qf[kc], b, sacc[nt], 0, 0, 0);
      }
    }

    // scale into log2 domain + causal mask (diagonal tile only)
    float s2[4][4];
    const bool diag = (t == qtile);
#pragma unroll
    for (int nt = 0; nt < 4; nt++)
#pragma unroll
      for (int r = 0; r < 4; r++) {
        float v = sacc[nt][r] * sc;
        if (diag) {
          int qr = q0 + 16 * wv + quad * 4 + r;
          int kr = t * 64 + 16 * nt + l15;
          if (kr > qr) v = -1e30f;
        }
        s2[nt][r] = v;
      }

    // online softmax; each row lives in the 16 lanes of one quad
    float mnew[4], alpha[4];
#pragma unroll
    for (int r = 0; r < 4; r++) {
      float tmax = fmaxf(fmaxf(s2[0][r], s2[1][r]), fmaxf(s2[2][r], s2[3][r]));
#pragma unroll
      for (int off = 1; off < 16; off <<= 1) tmax = fmaxf(tmax, __shfl_xor(tmax, off));
      mnew[r] = fmaxf(mrun[r], tmax);
      alpha[r] = exp2f(mrun[r] - mnew[r]);
      mrun[r] = mnew[r];
    }
    float p[4][4];
#pragma unroll
    for (int r = 0; r < 4; r++) {
      float s = 0.0f;
#pragma unroll
      for (int nt = 0; nt < 4; nt++) { p[nt][r] = exp2f(s2[nt][r] - mnew[r]); s += p[nt][r]; }
#pragma unroll
      for (int off = 1; off < 16; off <<= 1) s += __shfl_xor(s, off);
      lrun[r] = lrun[r] * alpha[r] + s;
    }
#pragma unroll
    for (int c = 0; c < 8; c++)
#pragma unroll
      for (int r = 0; r < 4; r++) o[c][r] *= alpha[r];

    // P: C-layout -> per-wave LDS (no barrier: DS in-order, Ps wave-private)
    u16* Pw = Ps + wv * 1024;
#pragma unroll
    for (int nt = 0; nt < 4; nt++)
#pragma unroll
      for (int r = 0; r < 4; r++) {
        int row = quad * 4 + r;
        int col = nt * 16 + l15;
        int cc = col >> 3, wi = col & 7;
        Pw[(row * 8 + (cc ^ (row & 7))) * 8 + wi] = f2bf(p[nt][r]);
      }

    // O += P V
#pragma unroll
    for (int kc = 0; kc < 2; kc++) {
      const int cl = kc * 4 + quad;
      bf16x8 a = *(const bf16x8*)((const char*)Pw + (l15 * 8 + (cl ^ (l15 & 7))) * 16);
#pragma unroll
      for (int c = 0; c < 8; c++) {
        int vr = 16 * c + l15;
        bf16x8 b = *(const bf16x8*)((const char*)Vs[cur] + (vr * 8 + (cl ^ (vr & 7))) * 16);
        o[c] = __builtin_amdgcn_mfma_f32_16x16x32_bf16(a, b, o[c], 0, 0, 0);
      }
    }
  }

  // store fp32 partial O + stats
  float* po = Opart + (size_t)slot * 64 * 128;
#pragma unroll
  for (int c = 0; c < 8; c++)
#pragma unroll
    for (int r = 0; r < 4; r++) {
      int ml = 16 * wv + quad * 4 + r;
      po[ml * 128 + 16 * c + l15] = o[c][r];
    }
  if (l15 == 0) {
#pragma unroll
    for (int r = 0; r < 4; r++) {
      int ml = 16 * wv + quad * 4 + r;
      mstat[slot * 64 + ml] = mrun[r];
      lstat[slot * 64 + ml] = lrun[r];
    }
  }
}

// ---------------------------------------------------------------------------
// Combine partials. grid (64 qtiles, 4 col-blocks), 256 threads.
// Thread handles one row x 8 cols. Output dtype per detected flag.
// ---------------------------------------------------------------------------
__global__ __launch_bounds__(256) void combine_kernel(
    const float* __restrict__ Opart, const float* __restrict__ mstat,
    const float* __restrict__ lstat, void* __restrict__ out_v,
    const int* __restrict__ dflag)
{
  const int q = blockIdx.x;
  const int cb = blockIdx.y;
  const int tid = threadIdx.x;
  const int row = tid >> 2;
  const int col = cb * 32 + (tid & 3) * 8;
  const int nch = (q + 4) / 4;   // ceil((q+1)/4)
  const bool of32 = (*dflag != 0);

  float M = -1e30f;
  {
    int base = 0;
    for (int c = 0; c < nch; c++) {
      int s = base + q - 4 * c;
      M = fmaxf(M, mstat[s * 64 + row]);
      base += 64 - 4 * c;
    }
  }
  float l = 0.0f;
  float acc[8];
#pragma unroll
  for (int j = 0; j < 8; j++) acc[j] = 0.0f;
  {
    int base = 0;
    for (int c = 0; c < nch; c++) {
      int s = base + q - 4 * c;
      float w = exp2f(mstat[s * 64 + row] - M);
      l += w * lstat[s * 64 + row];
      const float* op = Opart + ((size_t)s * 64 + row) * 128 + col;
      f32x4 a = *(const f32x4*)op;
      f32x4 b = *(const f32x4*)(op + 4);
#pragma unroll
      for (int j = 0; j < 4; j++) { acc[j] += w * a[j]; acc[4 + j] += w * b[j]; }
      base += 64 - 4 * c;
    }
  }
  const float inv = 1.0f / l;
  const size_t goff = (size_t)(q * 64 + row) * HS + col;
  if (of32) {
    float* out = (float*)out_v + goff;
    f32x4 r0, r1;
#pragma unroll
    for (int j = 0; j < 4; j++) { r0[j] = acc[j] * inv; r1[j] = acc[4 + j] * inv; }
    *(f32x4*)out = r0;
    *(f32x4*)(out + 4) = r1;
  } else {
    u16* out = (u16*)out_v + goff;
    us4 r0, r1;
#pragma unroll
    for (int j = 0; j < 4; j++) { r0[j] = f2bf(acc[j] * inv); r1[j] = f2bf(acc[4 + j] * inv); }
    *(us4*)out = r0;
    *(us4*)(out + 4) = r1;
  }
}

extern "C" void kernel_launch(void* const* d_in, const int* in_sizes, int n_in,
                              void* d_out, int out_size, void* d_ws, size_t ws_size,
                              hipStream_t stream) {
  const u16* x  = (const u16*)d_in[0];
  const u16* Wq = (const u16*)d_in[1];
  const u16* Wk = (const u16*)d_in[2];
  const u16* Wv = (const u16*)d_in[3];

  // ws layout (u16 units). The first region (partials) is written only by
  // attn_split, after qkv is done; Wb/Q/K/Vt live beyond it.
  float* Opart = (float*)d_ws;                   // 544 * 64*128 fp32 (17.8 MB)
  float* mstat = Opart + (size_t)544 * 64 * 128;
  float* lstat = mstat + (size_t)544 * 64;

  u16* Wqb = (u16*)(lstat + (size_t)544 * 64);   // 3 x 128*2048 bf16
  u16* Wkb = Wqb + (size_t)HS * D_IN;
  u16* Wvb = Wkb + (size_t)HS * D_IN;
  u16* Q   = Wvb + (size_t)HS * D_IN;            // 4096*128 bf16 each
  u16* K   = Q   + (size_t)T_TOK * HS;
  u16* Vt  = K   + (size_t)T_TOK * HS;
  int* flag = (int*)(Vt + (size_t)T_TOK * HS);

  conv3_kernel<<<384, 256, 0, stream>>>(Wq, Wk, Wv, Wqb, Wkb, Wvb, flag);
  qkv_kernel<<<dim3(256, 3), 256, 0, stream>>>(x, Wqb, Wkb, Wvb, Q, K, Vt);
  attn_split_kernel<<<dim3(64, NCH), 256, 0, stream>>>(Q, K, Vt, Opart, mstat, lstat);
  combine_kernel<<<dim3(64, 4), 256, 0, stream>>>(Opart, mstat, lstat, d_out, flag);
}